// Round 8
// baseline (211.397 us; speedup 1.0000x reference)
//
#include <hip/hip_runtime.h>
#include <hip/hip_bf16.h>

#define B_ 2
#define N_ 2048
#define E_ 1024
#define H_ 16
#define D_ 64
#define BH_ (B_ * H_)

typedef __attribute__((ext_vector_type(4))) float f32x4;
typedef __attribute__((ext_vector_type(8))) short bf16x8;
typedef __attribute__((ext_vector_type(4))) int i32x4;
typedef __attribute__((ext_vector_type(2))) int i32x2;
typedef __attribute__((ext_vector_type(4))) _Float16 f16x4;

#define MFMA(a, b, c) __builtin_amdgcn_mfma_f32_16x16x32_bf16(a, b, c, 0, 0, 0)
#define MFMA16(a, b, c) __builtin_amdgcn_mfma_f32_16x16x16f16(a, b, c, 0, 0, 0)

#define AS1(p) ((const __attribute__((address_space(1))) unsigned int*)(p))
#define AS3(p) ((__attribute__((address_space(3))) unsigned int*)(p))

static __device__ __forceinline__ int pack2bf(float lo, float hi) {
    __hip_bfloat162 t = __float22bfloat162_rn(float2{lo, hi});
    int r;
    __builtin_memcpy(&r, &t, 4);
    return r;
}
static __device__ __forceinline__ bf16x8 cvt8s(const float* __restrict__ p, float sc) {
    f32x4 a = *(const f32x4*)p;
    f32x4 b = *(const f32x4*)(p + 4);
    i32x4 r = {pack2bf(a.x * sc, a.y * sc), pack2bf(a.z * sc, a.w * sc),
               pack2bf(b.x * sc, b.y * sc), pack2bf(b.z * sc, b.w * sc)};
    return __builtin_bit_cast(bf16x8, r);
}
// 4x f32 -> f16x4 via two v_cvt_pkrtz_f16_f32 (RTZ; P in [0,1], fine)
static __device__ __forceinline__ f16x4 pack4f16(f32x4 p) {
    auto lo = __builtin_amdgcn_cvt_pkrtz(p.x, p.y);   // __fp16 x2
    auto hi = __builtin_amdgcn_cvt_pkrtz(p.z, p.w);
    f16x4 r;
    __builtin_memcpy(&r, &lo, 4);
    __builtin_memcpy(((char*)&r) + 4, &hi, 4);
    return r;
}

// ---------------------------------------------------------------------------
// Fused projections: z=0 -> qh = (q@Wq^T)*log2e/32, masked rows zeroed,
// layout [bh][n][d] bf16; z=1 -> kh [bh][n][d] bf16;
// z=2 -> vt [bh][d][n] in F16 (PV runs f16 16x16x16 MFMA);
// z=3 (when launched with gridDim.z==4) -> Wo fp32 -> bf16 convert.
// grid (N/64, BH, 3|4), block 256.   [r3-proven, untouched]
// ---------------------------------------------------------------------------
__global__ __launch_bounds__(256, 2)
void proj_kernel(const float* __restrict__ q, const float* __restrict__ k,
                 const float* __restrict__ v,
                 const float* __restrict__ Wq, const float* __restrict__ Wk,
                 const float* __restrict__ Wv,
                 const int* __restrict__ mask,
                 const float* __restrict__ Wo,
                 unsigned short* __restrict__ qh, unsigned short* __restrict__ kh,
                 unsigned short* __restrict__ vt, unsigned short* __restrict__ wob) {
    const int z = blockIdx.z;
    if (z == 3) {   // Wo fp32 -> bf16, 1024 blocks x 256 thr x 4 elems
        int idx = (blockIdx.y * 32 + blockIdx.x) * 256 + threadIdx.x;
        f32x4 w = *(const f32x4*)(Wo + (size_t)idx * 4);
        i32x2 r = {pack2bf(w.x, w.y), pack2bf(w.z, w.w)};
        *(i32x2*)(wob + (size_t)idx * 4) = r;
        return;
    }
    const float* X = (z == 0) ? q : (z == 1) ? k : v;
    const float* W = (z == 0) ? Wq : (z == 1) ? Wk : Wv;
    unsigned short* out = (z == 0) ? qh : (z == 1) ? kh : vt;
    const float wscale = (z == 0) ? (1.44269504f * 0.03125f) : 1.0f;

    const int lane = threadIdx.x & 63;
    const int wave = threadIdx.x >> 6;
    const int l16  = lane & 15;
    const int quad = lane >> 4;
    const int bh = blockIdx.y;
    const int b = bh >> 4, h = bh & 15;
    const int n0 = blockIdx.x * 64;
    const int tok = n0 + wave * 16 + l16;

    const float* xrow = X + ((size_t)(b * N_ + tok)) * E_ + h * 64;
    bf16x8 xf[2];
    xf[0] = cvt8s(xrow + quad * 8, 1.0f);
    xf[1] = cvt8s(xrow + 32 + quad * 8, 1.0f);

    const float* Wh = W + (size_t)h * 64 * 64;
    bf16x8 wf[4][2];
#pragma unroll
    for (int t4 = 0; t4 < 4; ++t4) {
        const float* wrow = Wh + (t4 * 16 + l16) * 64;
        wf[t4][0] = cvt8s(wrow + quad * 8, wscale);
        wf[t4][1] = cvt8s(wrow + 32 + quad * 8, wscale);
    }

    const int mk = (z == 0) ? mask[b * N_ + tok] : 1;

#pragma unroll
    for (int mi = 0; mi < 4; ++mi) {
        f32x4 a = {0.f, 0.f, 0.f, 0.f};
        a = MFMA(wf[mi][0], xf[0], a);   // D: row = dout, col = token (l16)
        a = MFMA(wf[mi][1], xf[1], a);
        if (z != 2) {
            i32x2 pk = {pack2bf(a.x, a.y), pack2bf(a.z, a.w)};
            if (!mk) pk = (i32x2){0, 0};
            *(i32x2*)(out + ((size_t)bh * N_ + tok) * 64 + mi * 16 + quad * 4) = pk;
        } else {
#pragma unroll
            for (int r = 0; r < 4; ++r) {
                int dout = mi * 16 + quad * 4 + r;
                _Float16 hv = (_Float16)a[r];
                unsigned short us;
                __builtin_memcpy(&us, &hv, 2);
                out[((size_t)bh * 64 + dout) * N_ + tok] = us;
            }
        }
    }
}

// ---------------------------------------------------------------------------
// Fallback (only if workspace too small for a non-aliased wob).
__global__ __launch_bounds__(256)
void cvt_wo_kernel(const float* __restrict__ wo, unsigned short* __restrict__ wob) {
    int idx = blockIdx.x * 256 + threadIdx.x;
    f32x4 v = *(const f32x4*)(wo + (size_t)idx * 4);
    i32x2 r = {pack2bf(v.x, v.y), pack2bf(v.z, v.w)};
    *(i32x2*)(wob + (size_t)idx * 4) = r;
}

// ---------------------------------------------------------------------------
// Flash attention v6: r2's proven per-tile body + ring-4 K/V buffers ->
// ONE barrier per TWO tiles (33 -> 17 barriers) with the PV(t-1)||QK(t)
// pipelining fully preserved (r6's mistake was serializing PV in-iter).
// Per pair (T, T+1): reg-prefetch K(T+2),K(T+3),V(T+1),V(T+2) ->
// half(T): QK(T)||PV(T-1), softmax(T) -> half(T+1): QK(T+1)||PV(T),
// softmax(T+1) -> LDS-write the 4 staged tiles -> barrier.
// Ring safety: reads {K:T,T+1; V:T-1,T} vs writes {K:T+2,T+3; V:T+1,T+2}
// are disjoint mod 4 -> single barrier race-free.
// LDS 4x[64][72] + 4x[64][76] = 75776 B -> still 2 blocks/CU.
// All per-instruction access patterns identical to r2 (measured 54.6us).
// grid (16,32)=512 (4 heads/XCD swizzle), block 256.
// ---------------------------------------------------------------------------
__global__ __launch_bounds__(256, 2)
void attn_kernel(const unsigned short* __restrict__ qh,
                 const unsigned short* __restrict__ kh,
                 const unsigned short* __restrict__ vt,
                 unsigned short* __restrict__ attnb) {
    __shared__ short Kb[4][64 * 72];   // 36 KB
    __shared__ short Vb[4][64 * 76];   // 38 KB   (total 75776 B)

    const int tid  = threadIdx.x;
    const int lane = tid & 63;
    const int wave = tid >> 6;
    const int l16  = lane & 15;
    const int quad = lane >> 4;

    const int flat = blockIdx.y * gridDim.x + blockIdx.x;   // 0..511
    const int qblk = flat >> 5;
    const int rem  = flat & 31;
    const int bh   = ((rem & 7) << 2) | (rem >> 3);          // 4 heads per XCD
    const int b = bh >> 4, h = bh & 15;
    const int q0 = qblk * 128 + wave * 32;

    const unsigned short* kbase = kh + (size_t)bh * N_ * 64;
    const unsigned short* vbase = vt + (size_t)bh * 64 * N_;

    const int c0i = tid;
    const int c1i = tid + 256;
    const int k0o = (c0i >> 3) * 72 + (c0i & 7) * 8;
    const int k1o = (c1i >> 3) * 72 + (c1i & 7) * 8;
    const int v0o = (c0i >> 3) * 76 + (c0i & 7) * 8;
    const int v1o = (c1i >> 3) * 76 + (c1i & 7) * 8;
    const int vr0 = c0i >> 3, vc0 = (c0i & 7) * 8;   // V global row/col8 chunk0
    const int vr1 = c1i >> 3, vc1 = (c1i & 7) * 8;   // V global row/col8 chunk1

    bf16x8 qf[2][2];
#pragma unroll
    for (int qi = 0; qi < 2; ++qi) {
        const unsigned short* qrow = qh + ((size_t)bh * N_ + q0 + qi * 16 + l16) * 64;
        qf[qi][0] = *(const bf16x8*)(qrow + quad * 8);
        qf[qi][1] = *(const bf16x8*)(qrow + 32 + quad * 8);
    }

    f32x4 psum[2] = {{0.f, 0.f, 0.f, 0.f}, {0.f, 0.f, 0.f, 0.f}};
    f32x4 o[4][2];
#pragma unroll
    for (int mi = 0; mi < 4; ++mi)
#pragma unroll
        for (int qi = 0; qi < 2; ++qi) o[mi][qi] = (f32x4){0.f, 0.f, 0.f, 0.f};

    f16x4 pf[2][4];   // saved P frags (16x16x16 B-operand) from previous tile

    // prologue: K0 -> Kb[0], K1 -> Kb[1], V0 -> Vb[0]
    {
        bf16x8 a0 = *(const bf16x8*)(kbase + c0i * 8);
        bf16x8 a1 = *(const bf16x8*)(kbase + c1i * 8);
        bf16x8 b0 = *(const bf16x8*)(kbase + 4096 + c0i * 8);
        bf16x8 b1 = *(const bf16x8*)(kbase + 4096 + c1i * 8);
        bf16x8 w0 = *(const bf16x8*)(vbase + (size_t)vr0 * N_ + vc0);
        bf16x8 w1 = *(const bf16x8*)(vbase + (size_t)vr1 * N_ + vc1);
        *(bf16x8*)(&Kb[0][0] + k0o) = a0;
        *(bf16x8*)(&Kb[0][0] + k1o) = a1;
        *(bf16x8*)(&Kb[1][0] + k0o) = b0;
        *(bf16x8*)(&Kb[1][0] + k1o) = b1;
        *(bf16x8*)(&Vb[0][0] + v0o) = w0;
        *(bf16x8*)(&Vb[0][0] + v1o) = w1;
    }
    __syncthreads();

// One 64-key tile: QK from KBUF || PV(prev tile) from VPREV, then softmax->pf.
// Exactly r2's inner body (same LDS access patterns), staging removed.
#define QKHALF(KBUF, VPREV, DO_PV)                                               \
    {                                                                            \
        __builtin_amdgcn_s_setprio(1);                                           \
        bf16x8 ka[4][2];                                                         \
        _Pragma("unroll")                                                        \
        for (int t4 = 0; t4 < 4; ++t4) {                                         \
            ka[t4][0] = *(const bf16x8*)((KBUF) + (t4 * 16 + l16) * 72 +         \
                                         quad * 8);                              \
            ka[t4][1] = *(const bf16x8*)((KBUF) + (t4 * 16 + l16) * 72 + 32 +    \
                                         quad * 8);                              \
        }                                                                        \
        f32x4 s[2][4];                                                           \
        _Pragma("unroll")                                                        \
        for (int qi = 0; qi < 2; ++qi)                                           \
            _Pragma("unroll")                                                    \
            for (int t4 = 0; t4 < 4; ++t4) {                                     \
                f32x4 z = {0.f, 0.f, 0.f, 0.f};                                  \
                z = MFMA(ka[t4][0], qf[qi][0], z);                               \
                z = MFMA(ka[t4][1], qf[qi][1], z);                               \
                s[qi][t4] = z;                                                   \
            }                                                                    \
        if (DO_PV) {                                                             \
            _Pragma("unroll")                                                    \
            for (int mi = 0; mi < 4; ++mi) {                                     \
                _Pragma("unroll")                                                \
                for (int t4 = 0; t4 < 4; ++t4) {                                 \
                    f16x4 va = *(const f16x4*)((VPREV) + (mi * 16 + l16) * 76 +  \
                                               t4 * 16 + quad * 4);              \
                    _Pragma("unroll")                                            \
                    for (int qi = 0; qi < 2; ++qi)                               \
                        o[mi][qi] = MFMA16(va, pf[qi][t4], o[mi][qi]);           \
                }                                                                \
            }                                                                    \
        }                                                                        \
        __builtin_amdgcn_s_setprio(0);                                           \
        _Pragma("unroll")                                                        \
        for (int qi = 0; qi < 2; ++qi)                                           \
            _Pragma("unroll")                                                    \
            for (int t4 = 0; t4 < 4; ++t4) {                                     \
                f32x4 p;                                                         \
                _Pragma("unroll")                                                \
                for (int r = 0; r < 4; ++r)                                      \
                    p[r] = __builtin_amdgcn_exp2f(s[qi][t4][r]);                 \
                psum[qi] += p;                                                   \
                pf[qi][t4] = pack4f16(p);                                        \
            }                                                                    \
    }

// Pair of tiles (T, T+1): prefetch K(T+2),K(T+3)->KC,KD and V(T+1),V(T+2)
// ->VR,VS; run the two halves; write staged tiles; ONE barrier.
#define PAIR(T, KA, KB, KC, KD, VP, VQ, VR, VS)                                  \
    {                                                                            \
        bf16x8 gKc0 = {}, gKc1 = {}, gKd0 = {}, gKd1 = {};                       \
        bf16x8 gVr0 = {}, gVr1 = {}, gVs0 = {}, gVs1 = {};                       \
        const bool stK = (T) + 2 < 32;                                           \
        const bool stVr = (T) + 1 < 32;                                          \
        const bool stVs = (T) + 2 < 32;                                          \
        if (stK) {                                                               \
            const unsigned short* kp = kbase + (size_t)((T) + 2) * 4096;         \
            gKc0 = *(const bf16x8*)(kp + c0i * 8);                               \
            gKc1 = *(const bf16x8*)(kp + c1i * 8);                               \
            gKd0 = *(const bf16x8*)(kp + 4096 + c0i * 8);                        \
            gKd1 = *(const bf16x8*)(kp + 4096 + c1i * 8);                        \
        }                                                                        \
        if (stVr) {                                                              \
            const int kc = ((T) + 1) * 64;                                       \
            gVr0 = *(const bf16x8*)(vbase + (size_t)vr0 * N_ + kc + vc0);        \
            gVr1 = *(const bf16x8*)(vbase + (size_t)vr1 * N_ + kc + vc1);        \
        }                                                                        \
        if (stVs) {                                                              \
            const int kc = ((T) + 2) * 64;                                       \
            gVs0 = *(const bf16x8*)(vbase + (size_t)vr0 * N_ + kc + vc0);        \
            gVs1 = *(const bf16x8*)(vbase + (size_t)vr1 * N_ + kc + vc1);        \
        }                                                                        \
        QKHALF(KA, VP, (T) > 0)                                                  \
        QKHALF(KB, VQ, true)                                                     \
        if (stK) {                                                               \
            *(bf16x8*)((KC) + k0o) = gKc0;                                       \
            *(bf16x8*)((KC) + k1o) = gKc1;                                       \
            *(bf16x8*)((KD) + k0o) = gKd0;                                       \
            *(bf16x8*)((KD) + k1o) = gKd1;                                       \
        }                                                                        \
        if (stVr) {                                                              \
            *(bf16x8*)((VR) + v0o) = gVr0;                                       \
            *(bf16x8*)((VR) + v1o) = gVr1;                                       \
        }                                                                        \
        if (stVs) {                                                              \
            *(bf16x8*)((VS) + v0o) = gVs0;                                       \
            *(bf16x8*)((VS) + v1o) = gVs1;                                       \
        }                                                                        \
        __syncthreads();                                                         \
    }

    for (int T = 0; T < 32; T += 4) {
        PAIR(T,     &Kb[0][0], &Kb[1][0], &Kb[2][0], &Kb[3][0],
                    &Vb[3][0], &Vb[0][0], &Vb[1][0], &Vb[2][0])
        PAIR(T + 2, &Kb[2][0], &Kb[3][0], &Kb[0][0], &Kb[1][0],
                    &Vb[1][0], &Vb[2][0], &Vb[3][0], &Vb[0][0])
    }
#undef PAIR
#undef QKHALF

    // drain: PV for tile 31 (V31 sits in Vb[31&3] = Vb[3], barrier'd)
    __builtin_amdgcn_s_setprio(1);
#pragma unroll
    for (int mi = 0; mi < 4; ++mi) {
#pragma unroll
        for (int t4 = 0; t4 < 4; ++t4) {
            f16x4 va = *(const f16x4*)(&Vb[3][0] + (mi * 16 + l16) * 76 +
                                       t4 * 16 + quad * 4);
#pragma unroll
            for (int qi = 0; qi < 2; ++qi)
                o[mi][qi] = MFMA16(va, pf[qi][t4], o[mi][qi]);
        }
    }
    __builtin_amdgcn_s_setprio(0);

    // row-sum reduction (once per kernel)
#pragma unroll
    for (int qi = 0; qi < 2; ++qi) {
        float rs = psum[qi].x + psum[qi].y + psum[qi].z + psum[qi].w;
        rs += __shfl_xor(rs, 16);
        rs += __shfl_xor(rs, 32);
        const float inv = 1.0f / rs;
        const int qrow_idx = q0 + qi * 16 + l16;
#pragma unroll
        for (int mi = 0; mi < 4; ++mi) {
            f32x4 ov = o[mi][qi];
            i32x2 pkk = {pack2bf(ov.x * inv, ov.y * inv),
                         pack2bf(ov.z * inv, ov.w * inv)};
            int d0 = mi * 16 + quad * 4;
            *(i32x2*)(attnb + ((size_t)(b * N_ + qrow_idx)) * E_ + h * 64 + d0) = pkk;
        }
    }
}

// ---------------------------------------------------------------------------
// out = attnb(4096x1024 bf16) @ wob^T(1024x1024) -> fp32.  128x128 tile,
// BK=32, global_load_lds w16, dbuf chunk-linear LDS, 512 thr, XCD-chunked
// block mapping (blocks sharing an A row-slab sit on one XCD's L2).
// grid 256 1-D.   [r3-proven, untouched]
// ---------------------------------------------------------------------------
__global__ __launch_bounds__(512, 1)
void out_gemm_kernel(const unsigned short* __restrict__ A,
                     const unsigned short* __restrict__ Bw,
                     float* __restrict__ out) {
    __shared__ short As[2][128 * 32];   // 8 KB each
    __shared__ short Bs[2][128 * 32];

    const int tid  = threadIdx.x;
    const int lane = tid & 63;
    const int l16  = lane & 15;
    const int quad = lane >> 4;
    const int wave = tid >> 6;
    const int wm = wave & 1, wn = wave >> 1;

    const int flat = blockIdx.x;          // 0..255
    const int xcd  = flat & 7;
    const int sub  = flat >> 3;           // 0..31
    const int m0 = (xcd * 4 + (sub >> 3)) * 128;   // 32 m-tiles
    const int n0 = (sub & 7) * 128;                // 8 n-tiles

    const unsigned short* gA = A + (size_t)m0 * E_;
    const unsigned short* gB = Bw + (size_t)n0 * E_;

    f32x4 acc[4][2];
#pragma unroll
    for (int mt = 0; mt < 4; ++mt)
#pragma unroll
        for (int nt = 0; nt < 2; ++nt) acc[mt][nt] = (f32x4){0.f, 0.f, 0.f, 0.f};

    const int cc = tid >> 7, rr = tid & 127;
#define OG_STAGE(buf, k0)                                                        \
    {                                                                            \
        __builtin_amdgcn_global_load_lds(AS1(gA + (size_t)rr * E_ + (k0) + cc * 8), \
                                         AS3(&As[buf][tid * 8]), 16, 0, 0);      \
        __builtin_amdgcn_global_load_lds(AS1(gB + (size_t)rr * E_ + (k0) + cc * 8), \
                                         AS3(&Bs[buf][tid * 8]), 16, 0, 0);      \
    }

    OG_STAGE(0, 0)
    __syncthreads();

    for (int kt = 0; kt < E_ / 32; ++kt) {
        const int cur = kt & 1;
        if (kt + 1 < E_ / 32) OG_STAGE(cur ^ 1, (kt + 1) * 32)

        bf16x8 af[4], bf[2];
#pragma unroll
        for (int mt = 0; mt < 4; ++mt)
            af[mt] = *(const bf16x8*)(&As[cur][(quad * 128 + wm * 64 + mt * 16 + l16) * 8]);
#pragma unroll
        for (int nt = 0; nt < 2; ++nt)
            bf[nt] = *(const bf16x8*)(&Bs[cur][(quad * 128 + wn * 32 + nt * 16 + l16) * 8]);

        __builtin_amdgcn_s_setprio(1);
#pragma unroll
        for (int mt = 0; mt < 4; ++mt)
#pragma unroll
            for (int nt = 0; nt < 2; ++nt)
                acc[mt][nt] = MFMA(af[mt], bf[nt], acc[mt][nt]);
        __builtin_amdgcn_s_setprio(0);

        __syncthreads();
    }

#pragma unroll
    for (int mt = 0; mt < 4; ++mt)
#pragma unroll
        for (int nt = 0; nt < 2; ++nt)
#pragma unroll
            for (int r = 0; r < 4; ++r)
                out[(size_t)(m0 + wm * 64 + mt * 16 + quad * 4 + r) * E_ +
                    n0 + wn * 32 + nt * 16 + l16] = acc[mt][nt][r];
#undef OG_STAGE
}

// ---------------------------------------------------------------------------
extern "C" void kernel_launch(void* const* d_in, const int* in_sizes, int n_in,
                              void* d_out, int out_size, void* d_ws, size_t ws_size,
                              hipStream_t stream) {
    const float* q    = (const float*)d_in[0];
    const float* k    = (const float*)d_in[1];
    const float* v    = (const float*)d_in[2];
    const int*   mask = (const int*)d_in[3];
    const float* Wq   = (const float*)d_in[4];
    const float* Wk   = (const float*)d_in[5];
    const float* Wv   = (const float*)d_in[6];
    const float* Wo   = (const float*)d_in[7];
    float* out = (float*)d_out;

    char* ws = (char*)d_ws;
    unsigned short* qh    = (unsigned short*)(ws);
    unsigned short* kh    = (unsigned short*)(ws + (size_t)8 * 1024 * 1024);
    unsigned short* vt    = (unsigned short*)(ws + (size_t)16 * 1024 * 1024);
    unsigned short* attnb = (unsigned short*)(ws + (size_t)24 * 1024 * 1024);

    const bool fused_wo = ws_size >= (size_t)34 * 1024 * 1024;
    unsigned short* wob = fused_wo ? (unsigned short*)(ws + (size_t)32 * 1024 * 1024)
                                   : (unsigned short*)(ws);

    dim3 blk(256);
    proj_kernel<<<dim3(N_ / 64, BH_, fused_wo ? 4 : 3), blk, 0, stream>>>(
        q, k, v, Wq, Wk, Wv, mask, Wo, qh, kh, vt, wob);
    attn_kernel<<<dim3(16, 32), blk, 0, stream>>>(qh, kh, vt, attnb);
    if (!fused_wo)
        cvt_wo_kernel<<<dim3(E_ * E_ / 1024), blk, 0, stream>>>(Wo, wob);
    out_gemm_kernel<<<dim3(256), dim3(512), 0, stream>>>(attnb, wob, out);
}

// Round 9
// 198.280 us; speedup vs baseline: 1.0662x; 1.0662x over previous
//
#include <hip/hip_runtime.h>
#include <hip/hip_bf16.h>

#define B_ 2
#define N_ 2048
#define E_ 1024
#define H_ 16
#define D_ 64
#define BH_ (B_ * H_)

typedef __attribute__((ext_vector_type(4))) float f32x4;
typedef __attribute__((ext_vector_type(8))) short bf16x8;
typedef __attribute__((ext_vector_type(4))) short s16x4;
typedef __attribute__((ext_vector_type(4))) int i32x4;
typedef __attribute__((ext_vector_type(2))) int i32x2;
typedef __attribute__((ext_vector_type(4))) _Float16 f16x4;

#define MFMA(a, b, c) __builtin_amdgcn_mfma_f32_16x16x32_bf16(a, b, c, 0, 0, 0)
#define MFMA16(a, b, c) __builtin_amdgcn_mfma_f32_16x16x16f16(a, b, c, 0, 0, 0)

#define AS1(p) ((const __attribute__((address_space(1))) unsigned int*)(p))
#define AS3(p) ((__attribute__((address_space(3))) unsigned int*)(p))

static __device__ __forceinline__ int pack2bf(float lo, float hi) {
    __hip_bfloat162 t = __float22bfloat162_rn(float2{lo, hi});
    int r;
    __builtin_memcpy(&r, &t, 4);
    return r;
}
static __device__ __forceinline__ bf16x8 cvt8s(const float* __restrict__ p, float sc) {
    f32x4 a = *(const f32x4*)p;
    f32x4 b = *(const f32x4*)(p + 4);
    i32x4 r = {pack2bf(a.x * sc, a.y * sc), pack2bf(a.z * sc, a.w * sc),
               pack2bf(b.x * sc, b.y * sc), pack2bf(b.z * sc, b.w * sc)};
    return __builtin_bit_cast(bf16x8, r);
}
// 4x f32 -> f16x4 via two v_cvt_pkrtz_f16_f32 (RTZ; P in [0,1], fine)
static __device__ __forceinline__ f16x4 pack4f16(f32x4 p) {
    auto lo = __builtin_amdgcn_cvt_pkrtz(p.x, p.y);   // __fp16 x2
    auto hi = __builtin_amdgcn_cvt_pkrtz(p.z, p.w);
    f16x4 r;
    __builtin_memcpy(&r, &lo, 4);
    __builtin_memcpy(((char*)&r) + 4, &hi, 4);
    return r;
}

// ---------------------------------------------------------------------------
// Fused projections: z=0 -> qh = (q@Wq^T)*log2e/32, masked rows zeroed,
// layout [bh][n][d] bf16; z=1 -> kh [bh][n][d] bf16;
// z=2 -> vt [bh][d][n] in F16 (PV runs f16 16x16x16 MFMA);
// z=3 (when launched with gridDim.z==4) -> Wo fp32 -> bf16 convert.
// grid (N/64, BH, 3|4), block 256.   [r3-proven]
// ---------------------------------------------------------------------------
__global__ __launch_bounds__(256, 2)
void proj_kernel(const float* __restrict__ q, const float* __restrict__ k,
                 const float* __restrict__ v,
                 const float* __restrict__ Wq, const float* __restrict__ Wk,
                 const float* __restrict__ Wv,
                 const int* __restrict__ mask,
                 const float* __restrict__ Wo,
                 unsigned short* __restrict__ qh, unsigned short* __restrict__ kh,
                 unsigned short* __restrict__ vt, unsigned short* __restrict__ wob) {
    const int z = blockIdx.z;
    if (z == 3) {   // Wo fp32 -> bf16, 1024 blocks x 256 thr x 4 elems
        int idx = (blockIdx.y * 32 + blockIdx.x) * 256 + threadIdx.x;
        f32x4 w = *(const f32x4*)(Wo + (size_t)idx * 4);
        i32x2 r = {pack2bf(w.x, w.y), pack2bf(w.z, w.w)};
        *(i32x2*)(wob + (size_t)idx * 4) = r;
        return;
    }
    const float* X = (z == 0) ? q : (z == 1) ? k : v;
    const float* W = (z == 0) ? Wq : (z == 1) ? Wk : Wv;
    unsigned short* out = (z == 0) ? qh : (z == 1) ? kh : vt;
    const float wscale = (z == 0) ? (1.44269504f * 0.03125f) : 1.0f;

    const int lane = threadIdx.x & 63;
    const int wave = threadIdx.x >> 6;
    const int l16  = lane & 15;
    const int quad = lane >> 4;
    const int bh = blockIdx.y;
    const int b = bh >> 4, h = bh & 15;
    const int n0 = blockIdx.x * 64;
    const int tok = n0 + wave * 16 + l16;

    const float* xrow = X + ((size_t)(b * N_ + tok)) * E_ + h * 64;
    bf16x8 xf[2];
    xf[0] = cvt8s(xrow + quad * 8, 1.0f);
    xf[1] = cvt8s(xrow + 32 + quad * 8, 1.0f);

    const float* Wh = W + (size_t)h * 64 * 64;
    bf16x8 wf[4][2];
#pragma unroll
    for (int t4 = 0; t4 < 4; ++t4) {
        const float* wrow = Wh + (t4 * 16 + l16) * 64;
        wf[t4][0] = cvt8s(wrow + quad * 8, wscale);
        wf[t4][1] = cvt8s(wrow + 32 + quad * 8, wscale);
    }

    const int mk = (z == 0) ? mask[b * N_ + tok] : 1;

#pragma unroll
    for (int mi = 0; mi < 4; ++mi) {
        f32x4 a = {0.f, 0.f, 0.f, 0.f};
        a = MFMA(wf[mi][0], xf[0], a);   // D: row = dout, col = token (l16)
        a = MFMA(wf[mi][1], xf[1], a);
        if (z != 2) {
            i32x2 pk = {pack2bf(a.x, a.y), pack2bf(a.z, a.w)};
            if (!mk) pk = (i32x2){0, 0};
            *(i32x2*)(out + ((size_t)bh * N_ + tok) * 64 + mi * 16 + quad * 4) = pk;
        } else {
#pragma unroll
            for (int r = 0; r < 4; ++r) {
                int dout = mi * 16 + quad * 4 + r;
                _Float16 hv = (_Float16)a[r];
                unsigned short us;
                __builtin_memcpy(&us, &hv, 2);
                out[((size_t)bh * 64 + dout) * N_ + tok] = us;
            }
        }
    }
}

// ---------------------------------------------------------------------------
// Fallback (only if workspace too small for a non-aliased wob).
__global__ __launch_bounds__(256)
void cvt_wo_kernel(const float* __restrict__ wo, unsigned short* __restrict__ wob) {
    int idx = blockIdx.x * 256 + threadIdx.x;
    f32x4 v = *(const f32x4*)(wo + (size_t)idx * 4);
    i32x2 r = {pack2bf(v.x, v.y), pack2bf(v.z, v.w)};
    *(i32x2*)(wob + (size_t)idx * 4) = r;
}

// ---------------------------------------------------------------------------
// Flash attention (r2-proven structure, measured 54.6-56.4 us; FINAL).
// PV uses v_mfma_f32_16x16x16_f16 whose B-operand layout EQUALS the QK C/D
// layout -> P needs NO cross-lane transform.  V stored/staged as f16.
// K dbuf [64][72]; V triple-buffer [64][76] (2-way residue conflicts only).
// PV(t-1) pipelined behind QK(t) as an independent dependency chain.
// No-max softmax; qh pre-scaled+masked at proj.  One barrier/iter.
// grid (16,32)=512 (XCD swizzle: 4 heads/XCD).  setprio around MFMA.
// Falsified alternatives: DMA staging+128-thr blocks (67.5), 64q/3blk
// (73.2), L2-direct no-LDS (180.7), KVBLK=128 serial-PV (57.4),
// ring-4 reg-prefetch (70.0: VGPR 128 + scratch spills, WRITE 8->43MB).
// ---------------------------------------------------------------------------
__global__ __launch_bounds__(256, 2)
void attn_kernel(const unsigned short* __restrict__ qh,
                 const unsigned short* __restrict__ kh,
                 const unsigned short* __restrict__ vt,
                 unsigned short* __restrict__ attnb) {
    __shared__ short Kb[2][64 * 72];   // 18 KB
    __shared__ short Vb[3][64 * 76];   // 28.5 KB

    const int tid  = threadIdx.x;
    const int lane = tid & 63;
    const int wave = tid >> 6;
    const int l16  = lane & 15;
    const int quad = lane >> 4;

    const int flat = blockIdx.y * gridDim.x + blockIdx.x;   // 0..511
    const int qblk = flat >> 5;
    const int rem  = flat & 31;
    const int bh   = ((rem & 7) << 2) | (rem >> 3);          // 4 heads per XCD
    const int b = bh >> 4, h = bh & 15;
    const int q0 = qblk * 128 + wave * 32;

    const unsigned short* kbase = kh + (size_t)bh * N_ * 64;
    const unsigned short* vbase = vt + (size_t)bh * 64 * N_;

    const int c0i = tid;
    const int c1i = tid + 256;
    const int k0o = (c0i >> 3) * 72 + (c0i & 7) * 8;
    const int k1o = (c1i >> 3) * 72 + (c1i & 7) * 8;
    const int v0o = (c0i >> 3) * 76 + (c0i & 7) * 8;
    const int v1o = (c1i >> 3) * 76 + (c1i & 7) * 8;

    short* kcur  = &Kb[0][0];
    short* knext = &Kb[1][0];
    short* vprev = &Vb[2][0];
    short* vcur  = &Vb[0][0];
    short* vnext = &Vb[1][0];

    bf16x8 qf[2][2];
#pragma unroll
    for (int qi = 0; qi < 2; ++qi) {
        const unsigned short* qrow = qh + ((size_t)bh * N_ + q0 + qi * 16 + l16) * 64;
        qf[qi][0] = *(const bf16x8*)(qrow + quad * 8);
        qf[qi][1] = *(const bf16x8*)(qrow + 32 + quad * 8);
    }

    f32x4 psum[2] = {{0.f, 0.f, 0.f, 0.f}, {0.f, 0.f, 0.f, 0.f}};
    f32x4 o[4][2];
#pragma unroll
    for (int mi = 0; mi < 4; ++mi)
#pragma unroll
        for (int qi = 0; qi < 2; ++qi) o[mi][qi] = (f32x4){0.f, 0.f, 0.f, 0.f};

    f16x4 pf[2][4];   // saved P frags (16x16x16 B-operand) from previous tile

    // stage tile 0
    bf16x8 gK0, gK1, gV0, gV1;
    gK0 = *(const bf16x8*)(kbase + c0i * 8);
    gK1 = *(const bf16x8*)(kbase + c1i * 8);
    gV0 = *(const bf16x8*)(vbase + (size_t)(c0i >> 3) * N_ + (c0i & 7) * 8);
    gV1 = *(const bf16x8*)(vbase + (size_t)(c1i >> 3) * N_ + (c1i & 7) * 8);
    *(bf16x8*)(kcur + k0o) = gK0;
    *(bf16x8*)(kcur + k1o) = gK1;
    *(bf16x8*)(vcur + v0o) = gV0;
    *(bf16x8*)(vcur + v1o) = gV1;
    __syncthreads();

    for (int kt = 0; kt < N_ / 64; ++kt) {
        // global prefetch of tile kt+1
        if (kt + 1 < N_ / 64) {
            const int k0n = (kt + 1) * 64;
            gK0 = *(const bf16x8*)(kbase + (size_t)k0n * 64 + c0i * 8);
            gK1 = *(const bf16x8*)(kbase + (size_t)k0n * 64 + c1i * 8);
            gV0 = *(const bf16x8*)(vbase + (size_t)(c0i >> 3) * N_ + k0n + (c0i & 7) * 8);
            gV1 = *(const bf16x8*)(vbase + (size_t)(c1i >> 3) * N_ + k0n + (c1i & 7) * 8);
        }

        // K frags + QK^T for tile kt  (high prio: MFMA cluster)
        __builtin_amdgcn_s_setprio(1);
        bf16x8 ka[4][2];
#pragma unroll
        for (int t4 = 0; t4 < 4; ++t4) {
            ka[t4][0] = *(const bf16x8*)(kcur + (t4 * 16 + l16) * 72 + quad * 8);
            ka[t4][1] = *(const bf16x8*)(kcur + (t4 * 16 + l16) * 72 + 32 + quad * 8);
        }
        f32x4 s[2][4];
#pragma unroll
        for (int qi = 0; qi < 2; ++qi)
#pragma unroll
            for (int t4 = 0; t4 < 4; ++t4) {
                f32x4 z = {0.f, 0.f, 0.f, 0.f};
                z = MFMA(ka[t4][0], qf[qi][0], z);
                z = MFMA(ka[t4][1], qf[qi][1], z);
                s[qi][t4] = z;
            }

        // PV for tile kt-1 (independent of this iter's chain)
        if (kt > 0) {
#pragma unroll
            for (int mi = 0; mi < 4; ++mi) {
#pragma unroll
                for (int t4 = 0; t4 < 4; ++t4) {
                    f16x4 va = *(const f16x4*)(vprev + (mi * 16 + l16) * 76 +
                                               t4 * 16 + quad * 4);
#pragma unroll
                    for (int qi = 0; qi < 2; ++qi)
                        o[mi][qi] = MFMA16(va, pf[qi][t4], o[mi][qi]);
                }
            }
        }
        __builtin_amdgcn_s_setprio(0);

        // softmax tile kt -> pf (NO transform: C-layout == 16x16x16 B-layout)
#pragma unroll
        for (int qi = 0; qi < 2; ++qi) {
#pragma unroll
            for (int t4 = 0; t4 < 4; ++t4) {
                f32x4 p;
#pragma unroll
                for (int r = 0; r < 4; ++r) p[r] = __builtin_amdgcn_exp2f(s[qi][t4][r]);
                psum[qi] += p;
                pf[qi][t4] = pack4f16(p);
            }
        }

        // stage tile kt+1, one barrier
        if (kt + 1 < N_ / 64) {
            *(bf16x8*)(knext + k0o) = gK0;
            *(bf16x8*)(knext + k1o) = gK1;
            *(bf16x8*)(vnext + v0o) = gV0;
            *(bf16x8*)(vnext + v1o) = gV1;
            __syncthreads();
        }

        // rotate buffers
        short* t = kcur; kcur = knext; knext = t;
        short* tv = vprev; vprev = vcur; vcur = vnext; vnext = tv;
    }

    // drain: PV for the last tile
    __builtin_amdgcn_s_setprio(1);
#pragma unroll
    for (int mi = 0; mi < 4; ++mi) {
#pragma unroll
        for (int t4 = 0; t4 < 4; ++t4) {
            f16x4 va = *(const f16x4*)(vprev + (mi * 16 + l16) * 76 +
                                       t4 * 16 + quad * 4);
#pragma unroll
            for (int qi = 0; qi < 2; ++qi)
                o[mi][qi] = MFMA16(va, pf[qi][t4], o[mi][qi]);
        }
    }
    __builtin_amdgcn_s_setprio(0);

    // row-sum reduction (once per kernel, not per iter)
#pragma unroll
    for (int qi = 0; qi < 2; ++qi) {
        float rs = psum[qi].x + psum[qi].y + psum[qi].z + psum[qi].w;
        rs += __shfl_xor(rs, 16);
        rs += __shfl_xor(rs, 32);
        const float inv = 1.0f / rs;
        const int qrow_idx = q0 + qi * 16 + l16;
#pragma unroll
        for (int mi = 0; mi < 4; ++mi) {
            f32x4 ov = o[mi][qi];
            i32x2 pkk = {pack2bf(ov.x * inv, ov.y * inv),
                         pack2bf(ov.z * inv, ov.w * inv)};
            int d0 = mi * 16 + quad * 4;
            *(i32x2*)(attnb + ((size_t)(b * N_ + qrow_idx)) * E_ + h * 64 + d0) = pkk;
        }
    }
}

// ---------------------------------------------------------------------------
// out = attnb(4096x1024 bf16) @ wob^T(1024x1024) -> fp32.  128x128 tile,
// BK=32, global_load_lds w16, dbuf chunk-linear LDS, 512 thr, XCD-chunked
// block mapping (blocks sharing an A row-slab sit on one XCD's L2).
// grid 256 1-D.   [r3-proven]
// ---------------------------------------------------------------------------
__global__ __launch_bounds__(512, 1)
void out_gemm_kernel(const unsigned short* __restrict__ A,
                     const unsigned short* __restrict__ Bw,
                     float* __restrict__ out) {
    __shared__ short As[2][128 * 32];   // 8 KB each
    __shared__ short Bs[2][128 * 32];

    const int tid  = threadIdx.x;
    const int lane = tid & 63;
    const int l16  = lane & 15;
    const int quad = lane >> 4;
    const int wave = tid >> 6;
    const int wm = wave & 1, wn = wave >> 1;

    const int flat = blockIdx.x;          // 0..255
    const int xcd  = flat & 7;
    const int sub  = flat >> 3;           // 0..31
    const int m0 = (xcd * 4 + (sub >> 3)) * 128;   // 32 m-tiles
    const int n0 = (sub & 7) * 128;                // 8 n-tiles

    const unsigned short* gA = A + (size_t)m0 * E_;
    const unsigned short* gB = Bw + (size_t)n0 * E_;

    f32x4 acc[4][2];
#pragma unroll
    for (int mt = 0; mt < 4; ++mt)
#pragma unroll
        for (int nt = 0; nt < 2; ++nt) acc[mt][nt] = (f32x4){0.f, 0.f, 0.f, 0.f};

    const int cc = tid >> 7, rr = tid & 127;
#define OG_STAGE(buf, k0)                                                        \
    {                                                                            \
        __builtin_amdgcn_global_load_lds(AS1(gA + (size_t)rr * E_ + (k0) + cc * 8), \
                                         AS3(&As[buf][tid * 8]), 16, 0, 0);      \
        __builtin_amdgcn_global_load_lds(AS1(gB + (size_t)rr * E_ + (k0) + cc * 8), \
                                         AS3(&Bs[buf][tid * 8]), 16, 0, 0);      \
    }

    OG_STAGE(0, 0)
    __syncthreads();

    for (int kt = 0; kt < E_ / 32; ++kt) {
        const int cur = kt & 1;
        if (kt + 1 < E_ / 32) OG_STAGE(cur ^ 1, (kt + 1) * 32)

        bf16x8 af[4], bf[2];
#pragma unroll
        for (int mt = 0; mt < 4; ++mt)
            af[mt] = *(const bf16x8*)(&As[cur][(quad * 128 + wm * 64 + mt * 16 + l16) * 8]);
#pragma unroll
        for (int nt = 0; nt < 2; ++nt)
            bf[nt] = *(const bf16x8*)(&Bs[cur][(quad * 128 + wn * 32 + nt * 16 + l16) * 8]);

        __builtin_amdgcn_s_setprio(1);
#pragma unroll
        for (int mt = 0; mt < 4; ++mt)
#pragma unroll
            for (int nt = 0; nt < 2; ++nt)
                acc[mt][nt] = MFMA(af[mt], bf[nt], acc[mt][nt]);
        __builtin_amdgcn_s_setprio(0);

        __syncthreads();
    }

#pragma unroll
    for (int mt = 0; mt < 4; ++mt)
#pragma unroll
        for (int nt = 0; nt < 2; ++nt)
#pragma unroll
            for (int r = 0; r < 4; ++r)
                out[(size_t)(m0 + wm * 64 + mt * 16 + quad * 4 + r) * E_ +
                    n0 + wn * 32 + nt * 16 + l16] = acc[mt][nt][r];
#undef OG_STAGE
}

// ---------------------------------------------------------------------------
extern "C" void kernel_launch(void* const* d_in, const int* in_sizes, int n_in,
                              void* d_out, int out_size, void* d_ws, size_t ws_size,
                              hipStream_t stream) {
    const float* q    = (const float*)d_in[0];
    const float* k    = (const float*)d_in[1];
    const float* v    = (const float*)d_in[2];
    const int*   mask = (const int*)d_in[3];
    const float* Wq   = (const float*)d_in[4];
    const float* Wk   = (const float*)d_in[5];
    const float* Wv   = (const float*)d_in[6];
    const float* Wo   = (const float*)d_in[7];
    float* out = (float*)d_out;

    char* ws = (char*)d_ws;
    unsigned short* qh    = (unsigned short*)(ws);
    unsigned short* kh    = (unsigned short*)(ws + (size_t)8 * 1024 * 1024);
    unsigned short* vt    = (unsigned short*)(ws + (size_t)16 * 1024 * 1024);
    unsigned short* attnb = (unsigned short*)(ws + (size_t)24 * 1024 * 1024);

    const bool fused_wo = ws_size >= (size_t)34 * 1024 * 1024;
    unsigned short* wob = fused_wo ? (unsigned short*)(ws + (size_t)32 * 1024 * 1024)
                                   : (unsigned short*)(ws);

    dim3 blk(256);
    proj_kernel<<<dim3(N_ / 64, BH_, fused_wo ? 4 : 3), blk, 0, stream>>>(
        q, k, v, Wq, Wk, Wv, mask, Wo, qh, kh, vt, wob);
    attn_kernel<<<dim3(16, 32), blk, 0, stream>>>(qh, kh, vt, attnb);
    if (!fused_wo)
        cvt_wo_kernel<<<dim3(E_ * E_ / 1024), blk, 0, stream>>>(Wo, wob);
    out_gemm_kernel<<<dim3(256), dim3(512), 0, stream>>>(attnb, wob, out);
}